// Round 6
// baseline (5542.216 us; speedup 1.0000x reference)
//
#include <hip/hip_runtime.h>

#define BB 256
#define TT 256
#define II 256
#define HH 1024
#define LL 128
#define K1 1280   // HH + II
#define GN 3072   // 3*HH

#define RP 49     // red row stride (floats): lane*49 % 32 banks -> 2-way max
#define GP 17     // gxn row stride
#define PP 20     // pred row stride

typedef short s8v    __attribute__((ext_vector_type(8)));
typedef float f32x4  __attribute__((ext_vector_type(4)));
typedef float f4v    __attribute__((ext_vector_type(4)));
typedef unsigned long long u64;

__device__ __forceinline__ unsigned short f2bf(float f) {
    unsigned u = __float_as_uint(f);
    u += 0x7fffu + ((u >> 16) & 1u);
    return (unsigned short)(u >> 16);
}
__device__ __forceinline__ float bf2f(unsigned short h) {
    return __uint_as_float(((unsigned)h) << 16);
}
__device__ __forceinline__ float sigm(float x) { return 1.0f / (1.0f + __expf(-x)); }

__device__ __forceinline__ s8v cvt8(const float* __restrict__ p) {
    const f4v lo = *(const f4v*)p;
    const f4v hi = *(const f4v*)(p + 4);
    s8v r;
    r[0] = (short)f2bf(lo[0]); r[1] = (short)f2bf(lo[1]);
    r[2] = (short)f2bf(lo[2]); r[3] = (short)f2bf(lo[3]);
    r[4] = (short)f2bf(hi[0]); r[5] = (short)f2bf(hi[1]);
    r[6] = (short)f2bf(hi[2]); r[7] = (short)f2bf(hi[3]);
    return r;
}

__device__ __forceinline__ s8v hload16a(const unsigned short* p) {
    union { u64 q[2]; s8v v; } u;
    u.q[0] = __hip_atomic_load((const u64*)p, __ATOMIC_RELAXED, __HIP_MEMORY_SCOPE_AGENT);
    u.q[1] = __hip_atomic_load((const u64*)p + 1, __ATOMIC_RELAXED, __HIP_MEMORY_SCOPE_AGENT);
    return u.v;
}
template<int FRESH> __device__ __forceinline__ s8v ld16h(const unsigned short* p) {
    if constexpr (FRESH) return *(const s8v*)p;
    else return hload16a(p);
}
template<int FRESH> __device__ __forceinline__ u64 ld8h(const unsigned short* p) {
    if constexpr (FRESH) return *(const u64*)p;
    else return __hip_atomic_load((const u64*)p, __ATOMIC_RELAXED, __HIP_MEMORY_SCOPE_AGENT);
}
__device__ __forceinline__ void st8h(unsigned short* p, u64 v) {
    __hip_atomic_store((u64*)p, v, __ATOMIC_RELAXED, __HIP_MEMORY_SCOPE_AGENT);
}

// poll one producer PAIR (flags p[0], p[1] >= t); uniform address -> broadcast
__device__ __forceinline__ void poll_pair(const unsigned* p, unsigned t) {
    if (t == 0) return;
    int guard = 0;
    for (;;) {
        u64 v = __hip_atomic_load((const u64*)p, __ATOMIC_RELAXED, __HIP_MEMORY_SCOPE_AGENT);
        if ((unsigned)v >= t && (unsigned)(v >> 32) >= t) return;
        __builtin_amdgcn_s_sleep(1);
        if (++guard > (1 << 17)) return;
    }
}
// poll 16 consecutive flags >= t (lr = lane&15)
__device__ __forceinline__ void poll_range16(const unsigned* p0, int lr, unsigned t) {
    if (t == 0) return;
    int guard = 0;
    for (;;) {
        unsigned v = __hip_atomic_load(p0 + lr, __ATOMIC_RELAXED, __HIP_MEMORY_SCOPE_AGENT);
        if (__ballot(v >= t) == ~0ull) break;
        __builtin_amdgcn_s_sleep(1);
        if (++guard > (1 << 17)) break;
    }
    asm volatile("" ::: "memory");
}
// poll all 64 flags >= t (lane 0..63)
__device__ __forceinline__ void poll_range64(const unsigned* p0, int lane, unsigned t) {
    if (t == 0) return;
    int guard = 0;
    for (;;) {
        unsigned v = __hip_atomic_load(p0 + lane, __ATOMIC_RELAXED, __HIP_MEMORY_SCOPE_AGENT);
        if (__ballot(v >= t) == ~0ull) break;
        __builtin_amdgcn_s_sleep(1);
        if (++guard > (1 << 17)) break;
    }
    asm volatile("" ::: "memory");
}

// ---- prep kernels ----
__global__ void k_prep_w(const float* __restrict__ Whh, const float* __restrict__ Wih,
                         unsigned short* __restrict__ Wperm) {
    int o = blockIdx.x;                 // 3072
    int ntt = o / 48, q = o - ntt * 48;
    int gate = q >> 4, j = ntt * 16 + (q & 15);
    int src = gate * HH + j;
    const float* sh = Whh + (size_t)src * HH;
    const float* si = Wih + (size_t)src * II;
    unsigned short* dst = Wperm + (size_t)o * K1;
    for (int k = threadIdx.x; k < K1; k += 256)
        dst[k] = f2bf(k < HH ? sh[k] : si[k - HH]);
}

__global__ void k_prep_misc(const float* __restrict__ bih, const float* __restrict__ bhh,
                            const float* __restrict__ Wout,
                            float* __restrict__ bihp, float* __restrict__ bhhp,
                            unsigned short* __restrict__ Woutb) {
    int idx = blockIdx.x * 256 + threadIdx.x;
    if (idx < GN) {
        int ntt = idx / 48, q = idx - ntt * 48;
        int gate = q >> 4, j = ntt * 16 + (q & 15);
        int src = gate * HH + j;
        bihp[idx] = bih[src];
        bhhp[idx] = bhh[src];
    }
    for (size_t i = (size_t)blockIdx.x * 256 + threadIdx.x; i < (size_t)II * HH;
         i += (size_t)gridDim.x * 256)
        Woutb[i] = f2bf(Wout[i]);
}

__global__ void k_h0(const float* __restrict__ z, const float* __restrict__ Wz,
                     const float* __restrict__ bz, unsigned short* __restrict__ hbuf) {
    int b = blockIdx.x;                 // 256
    int j0 = threadIdx.x * 4;
    const f4v* zr = (const f4v*)(z + (size_t)b * LL);
    u64 packed = 0;
#pragma unroll
    for (int jj = 0; jj < 4; ++jj) {
        int j = j0 + jj;
        const f4v* wr = (const f4v*)(Wz + (size_t)j * LL);
        float s = bz[j];
#pragma unroll
        for (int i = 0; i < LL / 4; ++i) {
            f4v a = zr[i], w = wr[i];
            s += a[0] * w[0] + a[1] * w[1] + a[2] * w[2] + a[3] * w[3];
        }
        packed |= (u64)f2bf(tanhf(s)) << (16 * jj);
    }
    *(u64*)(hbuf + (size_t)b * HH + j0) = packed;
}

// output projection: one 16x16 tile, K=1024 split across 4 waves
template<int FRESH>
__device__ __forceinline__ void proj_tile(
    const unsigned short* hb, const unsigned short* __restrict__ Woutb,
    float* __restrict__ out, float (*pred)[16 * PP],
    int brow, int io, int wave, int lane, int lr, int lk, int tp, float boutv) {
    f32x4 oa = {0.f, 0.f, 0.f, 0.f};
    const unsigned short* ap = hb + (size_t)(brow + lr) * HH + (wave << 8) + lk;
    const unsigned short* wp = Woutb + (size_t)(io * 16 + lr) * HH + (wave << 8) + lk;
#pragma unroll
    for (int ks = 0; ks < 8; ++ks) {
        s8v a = ld16h<FRESH>(ap + ks * 32);
        s8v w = *(const s8v*)(wp + ks * 32);
        oa = __builtin_amdgcn_mfma_f32_16x16x32_bf16(a, w, oa, 0, 0, 0);
    }
    if (wave >= 1) {
#pragma unroll
        for (int r = 0; r < 4; ++r)
            pred[wave - 1][(((lane >> 4) << 2) + r) * PP + lr] = oa[r];
    }
    __syncthreads();
    if (wave == 0) {
#pragma unroll
        for (int r = 0; r < 4; ++r) {
            int rw = ((lane >> 4) << 2) + r;
            int idx = rw * PP + lr;
            float v = oa[r] + pred[0][idx] + pred[1][idx] + pred[2][idx] + boutv;
            out[(size_t)(brow + rw) * (TT * II) + (size_t)tp * II + io * 16 + lr] = sigm(v);
        }
    }
    __syncthreads();
}

// grid 256 = 4 m-groups (64 batches) x 64 nt (16 hidden j -> 48 gate rows)
template<int FRESH>
__device__ void run(const float* __restrict__ tgt, const unsigned short* __restrict__ Wperm,
                    const float* __restrict__ bihp, const float* __restrict__ bhhp,
                    unsigned short* hbuf, const unsigned short* __restrict__ Woutb,
                    const float* __restrict__ bout, float* __restrict__ out,
                    unsigned* flags,
                    float (*red)[64 * RP], float* gxn, float (*pred)[16 * PP]) {
    const int tid = threadIdx.x;
    const int wave = tid >> 6, lane = tid & 63;
    const int lr = lane & 15;
    const int lk = (lane >> 4) << 3;
    const int bid = blockIdx.x;
    const int m = bid >> 6, nt = bid & 63;
    const int brow = m * 64 + (nt >> 4) * 16;
    const int io = nt & 15;
    const float boutv = bout[io * 16 + lr];

    // epilogue ownership: within a wave eb = lane, j4 = wave*4 (4 j -> one 8B store)
    const int eb = lane;
    const int j4 = wave << 2;
    const int ob = nt * 48;
    float bir[4], biz[4], bixn[4], bihn[4];
#pragma unroll
    for (int jj = 0; jj < 4; ++jj) {
        int j = j4 + jj;
        bir[jj]  = bihp[ob + j] + bhhp[ob + j];
        biz[jj]  = bihp[ob + 16 + j] + bhhp[ob + 16 + j];
        bixn[jj] = bihp[ob + 32 + j];
        bihn[jj] = bhhp[ob + 32 + j];
    }

    // hoist W slice into registers: 30 x 16B per lane (grid=256, 1 WG/CU, 512-VGPR budget)
    s8v wreg[30];
    if (wave == 3) {
#pragma unroll
        for (int ks = 0; ks < 2; ++ks)
#pragma unroll
            for (int ni = 0; ni < 3; ++ni)
                wreg[ks * 3 + ni] = *(const s8v*)(Wperm +
                    (size_t)(nt * 48 + ni * 16 + lr) * K1 + 960 + ks * 32 + lk);
#pragma unroll
        for (int ks = 0; ks < 8; ++ks)
#pragma unroll
            for (int ni = 0; ni < 3; ++ni)
                wreg[6 + ks * 3 + ni] = *(const s8v*)(Wperm +
                    (size_t)(nt * 48 + ni * 16 + lr) * K1 + HH + ks * 32 + lk);
    } else {
#pragma unroll
        for (int ks = 0; ks < 10; ++ks)
#pragma unroll
            for (int ni = 0; ni < 3; ++ni)
                wreg[ks * 3 + ni] = *(const s8v*)(Wperm +
                    (size_t)(nt * 48 + ni * 16 + lr) * K1 + wave * 320 + ks * 32 + lk);
    }

    unsigned* gflags = flags + (m << 6);

    for (int t = 0; t < TT; ++t) {
        const unsigned short* hcur = hbuf + (size_t)(FRESH ? t : (t % 3)) * (BB * HH);
        unsigned short* hnxt = hbuf + (size_t)(FRESH ? (t + 1) : ((t + 1) % 3)) * (BB * HH);

        f32x4 acc[12];
#pragma unroll
        for (int i = 0; i < 12; ++i) acc[i] = (f32x4){0.f, 0.f, 0.f, 0.f};
        f32x4 accx[4];
#pragma unroll
        for (int i = 0; i < 4; ++i) accx[i] = (f32x4){0.f, 0.f, 0.f, 0.f};

        // wave 3: x-part GEMM first (depends only on constant X)
        if (wave == 3) {
#pragma unroll
            for (int ks = 0; ks < 8; ++ks) {
                s8v xa[4];
#pragma unroll
                for (int mi = 0; mi < 4; ++mi)
                    xa[mi] = cvt8(tgt +
                        ((size_t)(m * 64 + mi * 16 + lr) * TT + t) * II + ks * 32 + lk);
#pragma unroll
                for (int mi = 0; mi < 4; ++mi) {
                    acc[mi * 3 + 0] = __builtin_amdgcn_mfma_f32_16x16x32_bf16(
                        xa[mi], wreg[6 + ks * 3 + 0], acc[mi * 3 + 0], 0, 0, 0);
                    acc[mi * 3 + 1] = __builtin_amdgcn_mfma_f32_16x16x32_bf16(
                        xa[mi], wreg[6 + ks * 3 + 1], acc[mi * 3 + 1], 0, 0, 0);
                    accx[mi] = __builtin_amdgcn_mfma_f32_16x16x32_bf16(
                        xa[mi], wreg[6 + ks * 3 + 2], accx[mi], 0, 0, 0);
                }
            }
        }

        if constexpr (!FRESH) {
            // 3-slot reuse needs bounded drift: full-group barrier
            if (wave == 0) poll_range64(gflags, lane, (unsigned)t);
            __syncthreads();
        }

        // chunked h-GEMM: poll producer pair per 32-k chunk, lookahead by one
        if (wave < 3) {
            const unsigned* fp = gflags + wave * 20;
            poll_pair(fp, (unsigned)t);
#pragma unroll
            for (int ci = 0; ci < 10; ++ci) {
                s8v a[4];
#pragma unroll
                for (int mi = 0; mi < 4; ++mi)
                    a[mi] = ld16h<FRESH>(hcur +
                        (size_t)(m * 64 + mi * 16 + lr) * HH + wave * 320 + ci * 32 + lk);
                if (ci < 9) poll_pair(fp + 2 * (ci + 1), (unsigned)t);  // overlap load latency
#pragma unroll
                for (int mi = 0; mi < 4; ++mi)
#pragma unroll
                    for (int ni = 0; ni < 3; ++ni)
                        acc[mi * 3 + ni] = __builtin_amdgcn_mfma_f32_16x16x32_bf16(
                            a[mi], wreg[ci * 3 + ni], acc[mi * 3 + ni], 0, 0, 0);
            }
        } else {
            poll_pair(gflags + 60, (unsigned)t);
#pragma unroll
            for (int ks = 0; ks < 2; ++ks) {
                s8v a[4];
#pragma unroll
                for (int mi = 0; mi < 4; ++mi)
                    a[mi] = ld16h<FRESH>(hcur +
                        (size_t)(m * 64 + mi * 16 + lr) * HH + 960 + ks * 32 + lk);
                if (ks == 0) poll_pair(gflags + 62, (unsigned)t);
#pragma unroll
                for (int mi = 0; mi < 4; ++mi)
#pragma unroll
                    for (int ni = 0; ni < 3; ++ni)
                        acc[mi * 3 + ni] = __builtin_amdgcn_mfma_f32_16x16x32_bf16(
                            a[mi], wreg[ks * 3 + ni], acc[mi * 3 + ni], 0, 0, 0);
            }
#pragma unroll
            for (int mi = 0; mi < 4; ++mi)
#pragma unroll
                for (int r = 0; r < 4; ++r)
                    gxn[(mi * 16 + ((lane >> 4) << 2) + r) * GP + lr] = accx[mi][r];
        }

        // all 4 waves write partials; epilogue sums the 4 sets directly
        {
            float* s = &red[wave][0];
#pragma unroll
            for (int mi = 0; mi < 4; ++mi)
#pragma unroll
                for (int ni = 0; ni < 3; ++ni)
#pragma unroll
                    for (int r = 0; r < 4; ++r)
                        s[(mi * 16 + ((lane >> 4) << 2) + r) * RP + ni * 16 + lr] =
                            acc[mi * 3 + ni][r];
        }
        __syncthreads();

        // gate epilogue: thread (eb, j4..j4+3) -> one packed 8B h store (sc1)
        {
            const int bg = m * 64 + eb;
            const int jg = nt * 16 + j4;
            u64 hold8 = ld8h<FRESH>(hcur + (size_t)bg * HH + jg);
            u64 packed = 0;
#pragma unroll
            for (int jj = 0; jj < 4; ++jj) {
                int c = j4 + jj;
                int i0 = eb * RP + c;
                float ghr = red[0][i0] + red[1][i0] + red[2][i0] + red[3][i0];
                float ghz = red[0][i0 + 16] + red[1][i0 + 16] + red[2][i0 + 16] + red[3][i0 + 16];
                float ghn = red[0][i0 + 32] + red[1][i0 + 32] + red[2][i0 + 32] + red[3][i0 + 32];
                float gx  = gxn[eb * GP + c];
                float r   = sigm(ghr + bir[jj]);
                float zg  = sigm(ghz + biz[jj]);
                float n   = tanhf(gx + bixn[jj] + r * (ghn + bihn[jj]));
                float ho  = bf2f((unsigned short)(hold8 >> (16 * jj)));
                packed |= (u64)f2bf((1.f - zg) * n + zg * ho) << (16 * jj);
            }
            st8h(hnxt + (size_t)bg * HH + jg, packed);
        }

        // arrive: drain stores, block-sync, one flag STORE per WG
        asm volatile("s_waitcnt vmcnt(0)" ::: "memory");
        __syncthreads();
        if (tid == 0)
            __hip_atomic_store(gflags + nt, (unsigned)(t + 1), __ATOMIC_RELAXED,
                               __HIP_MEMORY_SCOPE_AGENT);

        // project y_{t-1} from h_t while peers' flags fill (per-wave range poll)
        if (t > 0) {
            poll_range16(gflags + (wave << 4), lr, (unsigned)t);
            proj_tile<FRESH>(hcur, Woutb, out, pred, brow, io, wave, lane, lr, lk,
                             t - 1, boutv);
        }
    }

    // tail: y_{T-1} from h_T
    poll_range16(gflags + (wave << 4), lr, (unsigned)TT);
    proj_tile<FRESH>(hbuf + (size_t)(FRESH ? TT : (TT % 3)) * (BB * HH),
                     Woutb, out, pred, brow, io, wave, lane, lr, lk, TT - 1, boutv);
}

__global__ __launch_bounds__(256, 1) void dec_main(
    const float* __restrict__ tgt, const unsigned short* __restrict__ Wperm,
    const float* __restrict__ bihp, const float* __restrict__ bhhp,
    unsigned short* hbuf, const unsigned short* __restrict__ Woutb,
    const float* __restrict__ bout, float* __restrict__ out,
    unsigned* flags, int fresh) {
    __shared__ float red[4][64 * RP];
    __shared__ float gxn[64 * GP];
    __shared__ float pred[3][16 * PP];
    if (fresh)
        run<1>(tgt, Wperm, bihp, bhhp, hbuf, Woutb, bout, out, flags, red, gxn, pred);
    else
        run<0>(tgt, Wperm, bihp, bhhp, hbuf, Woutb, bout, out, flags, red, gxn, pred);
}

extern "C" void kernel_launch(void* const* d_in, const int* in_sizes, int n_in,
                              void* d_out, int out_size, void* d_ws, size_t ws_size,
                              hipStream_t stream) {
    const float* z    = (const float*)d_in[0];
    const float* tgt  = (const float*)d_in[2];
    const float* Wz2h = (const float*)d_in[3];
    const float* bz2h = (const float*)d_in[4];
    const float* Wih  = (const float*)d_in[5];
    const float* Whh  = (const float*)d_in[6];
    const float* bih  = (const float*)d_in[7];
    const float* bhh  = (const float*)d_in[8];
    const float* Wout = (const float*)d_in[9];
    const float* bout = (const float*)d_in[10];
    float* out = (float*)d_out;

    char* ws = (char*)d_ws;
    unsigned short* Wperm = (unsigned short*)ws;               // 7,864,320
    float* bihp           = (float*)(ws + 7864320);            //    12,288
    float* bhhp           = (float*)(ws + 7876608);            //    12,288
    unsigned short* Woutb = (unsigned short*)(ws + 7888896);   //   524,288
    unsigned* flags       = (unsigned*)(ws + 8413184);         //     1,024 (4 grp x 64)
    unsigned short* hbuf  = (unsigned short*)(ws + 8415232);   // 257 or 3 slots x 524,288

    const size_t need_big = 8415232ull + 257ull * 524288ull;   // ~143.1 MB
    const int fresh = (ws_size >= need_big) ? 1 : 0;

    hipMemsetAsync((void*)flags, 0, 1024, stream);
    hipLaunchKernelGGL(k_prep_w, dim3(GN), dim3(256), 0, stream, Whh, Wih, Wperm);
    hipLaunchKernelGGL(k_prep_misc, dim3(1024), dim3(256), 0, stream, bih, bhh, Wout,
                       bihp, bhhp, Woutb);
    hipLaunchKernelGGL(k_h0, dim3(BB), dim3(256), 0, stream, z, Wz2h, bz2h, hbuf);
    hipLaunchKernelGGL(dec_main, dim3(256), dim3(256), 0, stream,
                       tgt, Wperm, bihp, bhhp, hbuf, Woutb, bout, out, flags, fresh);
}